// Round 1
// baseline (52450.958 us; speedup 1.0000x reference)
//
#include <hip/hip_runtime.h>

// ---------- constants ----------
#define NX 64
#define NY 64
#define NZ 128
#define NH 512
#define HB 256
#define TX 64
#define TY 100
#define BSZ 1024
#define HOR 100
#define MH1 1024
#define MH2 512

__device__ __forceinline__ float sigf(float x) {
    return 1.0f / (1.0f + __expf(-x));
}
__device__ __forceinline__ float tanh_fast(float x) {
    // 1 - 2/(e^{2x}+1): safe at both extremes (exp->0 gives -1, exp->inf gives +1)
    float e = __expf(2.0f * x);
    return 1.0f - 2.0f / (e + 1.0f);
}

// ---------- encoder step: fused x@Wih^T + h@Whh^T + b -> LSTM cell -> h,c, +mean-acc
// 4 scans: 0=xr_f, 1=xr_b, 2=er_f, 3=er_b. Block = 64 rows x 64 hcols x 4 gate quadrants.
struct EncParams {
    const float* xin[4];
    const float* wih[4];
    const float* whh[4];
    const float* bih[4];
    const float* bhh[4];
    float* Hst[4];   // [2][BSZ*HB] double-buffered hidden
    float* Cst[4];   // [BSZ*HB]
    float* hsum[4];  // accumulation target (row stride 512), col offset pre-baked
};

__global__ __launch_bounds__(256) void enc_step(EncParams p, int t) {
    int sb = blockIdx.x >> 6;
    int scan = (t < TX) ? sb : (sb + 2);
    int tile = blockIdx.x & 63;
    int rt = tile & 15;  // 16 row tiles
    int ct = tile >> 4;  // 4 hcol tiles
    int row0 = rt * 64;
    int hc0 = ct * 64;

    int T = (scan < 2) ? TX : TY;
    int tt = (scan & 1) ? (T - 1 - t) : t;
    const float* __restrict__ xt = p.xin[scan] + (size_t)tt * BSZ * NX;
    const float* __restrict__ Hcur = p.Hst[scan] + (size_t)(t & 1) * BSZ * HB;
    float* __restrict__ Hnext = p.Hst[scan] + (size_t)((t + 1) & 1) * BSZ * HB;
    float* __restrict__ Cs = p.Cst[scan];
    const float* __restrict__ wih = p.wih[scan];
    const float* __restrict__ whh = p.whh[scan];
    const float* __restrict__ bih = p.bih[scan];
    const float* __restrict__ bhh = p.bhh[scan];
    float* __restrict__ hsum = p.hsum[scan];

    __shared__ float As[16][64];
    __shared__ float Bs[16][256];

    int tid = threadIdx.x;
    int tr = tid >> 4, tc = tid & 15;

    float acc[4][4][4];  // [quadrant][row][col]
#pragma unroll
    for (int q = 0; q < 4; ++q)
#pragma unroll
        for (int cc = 0; cc < 4; ++cc) {
            int n = q * HB + hc0 + tc * 4 + cc;
            float bv = bih[n] + bhh[n];
#pragma unroll
            for (int r = 0; r < 4; ++r) acc[q][r][cc] = bv;
        }

    for (int k0 = 0; k0 < NX + HB; k0 += 16) {
        bool isX = (k0 < NX);
#pragma unroll
        for (int e = tid; e < 64 * 16; e += 256) {
            int m = e >> 4, k = e & 15;
            float v;
            if (isX) v = xt[(row0 + m) * NX + k0 + k];
            else     v = Hcur[(row0 + m) * HB + (k0 - NX) + k];
            As[k][m] = v;
        }
#pragma unroll
        for (int e = tid; e < 256 * 16; e += 256) {
            int j = e >> 4, k = e & 15;
            int q = j >> 6;
            int n = q * HB + hc0 + (j & 63);
            float v;
            if (isX) v = wih[n * NX + k0 + k];
            else     v = whh[n * HB + (k0 - NX) + k];
            Bs[k][j] = v;
        }
        __syncthreads();
#pragma unroll
        for (int k = 0; k < 16; ++k) {
            float a[4];
#pragma unroll
            for (int r = 0; r < 4; ++r) a[r] = As[k][tr * 4 + r];
#pragma unroll
            for (int q = 0; q < 4; ++q)
#pragma unroll
                for (int cc = 0; cc < 4; ++cc) {
                    float b = Bs[k][q * 64 + tc * 4 + cc];
#pragma unroll
                    for (int r = 0; r < 4; ++r)
                        acc[q][r][cc] = fmaf(a[r], b, acc[q][r][cc]);
                }
        }
        __syncthreads();
    }

#pragma unroll
    for (int r = 0; r < 4; ++r) {
        int row = row0 + tr * 4 + r;
#pragma unroll
        for (int cc = 0; cc < 4; ++cc) {
            int hc = hc0 + tc * 4 + cc;
            float iv = sigf(acc[0][r][cc]);
            float fv = sigf(acc[1][r][cc]);
            float gv = tanh_fast(acc[2][r][cc]);
            float ov = sigf(acc[3][r][cc]);
            float cold = Cs[row * HB + hc];
            float cn = fv * cold + iv * gv;
            float hn = ov * tanh_fast(cn);
            Cs[row * HB + hc] = cn;
            Hnext[row * HB + hc] = hn;
            hsum[row * 512 + hc] += hn;
        }
    }
}

// ---------- decoder gate step: const_gates + yp@WihY^T + h@Whh^T -> cell ----------
__global__ __launch_bounds__(256) void dec_step(
    const float* __restrict__ yp,     // [BSZ, 64]
    const float* __restrict__ drwih,  // [2048, 704]
    const float* __restrict__ drwhh,  // [2048, 512]
    const float* __restrict__ cg,     // [BSZ, 2048] const gates incl biases
    const float* __restrict__ Hcur,   // [BSZ, 512]
    float* __restrict__ Hnext,
    float* __restrict__ Cs) {
    int rt = blockIdx.x & 15;
    int ct = blockIdx.x >> 4;  // 0..7
    int row0 = rt * 64, hc0 = ct * 64;

    __shared__ float As[16][64];
    __shared__ float Bs[16][256];

    int tid = threadIdx.x, tr = tid >> 4, tc = tid & 15;

    float acc[4][4][4];
#pragma unroll
    for (int q = 0; q < 4; ++q)
#pragma unroll
        for (int r = 0; r < 4; ++r) {
            int row = row0 + tr * 4 + r;
#pragma unroll
            for (int cc = 0; cc < 4; ++cc) {
                int n = q * NH + hc0 + tc * 4 + cc;
                acc[q][r][cc] = cg[(size_t)row * 2048 + n];
            }
        }

    for (int k0 = 0; k0 < NY + NH; k0 += 16) {
        bool isY = (k0 < NY);
#pragma unroll
        for (int e = tid; e < 64 * 16; e += 256) {
            int m = e >> 4, k = e & 15;
            float v;
            if (isY) v = yp[(row0 + m) * NY + k0 + k];
            else     v = Hcur[(row0 + m) * NH + (k0 - NY) + k];
            As[k][m] = v;
        }
#pragma unroll
        for (int e = tid; e < 256 * 16; e += 256) {
            int j = e >> 4, k = e & 15;
            int q = j >> 6;
            int n = q * NH + hc0 + (j & 63);
            float v;
            if (isY) v = drwih[(size_t)n * 704 + 640 + k0 + k];
            else     v = drwhh[(size_t)n * NH + (k0 - NY) + k];
            Bs[k][j] = v;
        }
        __syncthreads();
#pragma unroll
        for (int k = 0; k < 16; ++k) {
            float a[4];
#pragma unroll
            for (int r = 0; r < 4; ++r) a[r] = As[k][tr * 4 + r];
#pragma unroll
            for (int q = 0; q < 4; ++q)
#pragma unroll
                for (int cc = 0; cc < 4; ++cc) {
                    float b = Bs[k][q * 64 + tc * 4 + cc];
#pragma unroll
                    for (int r = 0; r < 4; ++r)
                        acc[q][r][cc] = fmaf(a[r], b, acc[q][r][cc]);
                }
        }
        __syncthreads();
    }

#pragma unroll
    for (int r = 0; r < 4; ++r) {
        int row = row0 + tr * 4 + r;
#pragma unroll
        for (int cc = 0; cc < 4; ++cc) {
            int hc = hc0 + tc * 4 + cc;
            float iv = sigf(acc[0][r][cc]);
            float fv = sigf(acc[1][r][cc]);
            float gv = tanh_fast(acc[2][r][cc]);
            float ov = sigf(acc[3][r][cc]);
            float cold = Cs[row * NH + hc];
            float cn = fv * cold + iv * gv;
            float hn = ov * tanh_fast(cn);
            Cs[row * NH + hc] = cn;
            Hnext[row * NH + hc] = hn;
        }
    }
}

// ---------- generic out = act(A @ W^T + b1 + b2) ----------
// A: [M,K] lda; W: [N,K] ldw; grid = (N/BN, M/BM); 256 threads.
template <int BM, int BN, int ACT>
__global__ __launch_bounds__(256) void gemm_ba(
    const float* __restrict__ A, int lda,
    const float* __restrict__ W, int ldw,
    const float* __restrict__ b1, const float* __restrict__ b2,
    float* __restrict__ out, int ldo, int K) {
    constexpr int BK = 16;
    constexpr int TM = BM / 16, TN = BN / 16;
    __shared__ float As[BK][BM];
    __shared__ float Bs[BK][BN];
    int row0 = blockIdx.y * BM, col0 = blockIdx.x * BN;
    int tid = threadIdx.x, tr = tid >> 4, tc = tid & 15;
    float acc[TM][TN] = {};
    for (int k0 = 0; k0 < K; k0 += BK) {
#pragma unroll
        for (int e = tid; e < BM * BK; e += 256) {
            int m = e / BK, k = e % BK;
            As[k][m] = A[(size_t)(row0 + m) * lda + k0 + k];
        }
#pragma unroll
        for (int e = tid; e < BN * BK; e += 256) {
            int n = e / BK, k = e % BK;
            Bs[k][n] = W[(size_t)(col0 + n) * ldw + k0 + k];
        }
        __syncthreads();
#pragma unroll
        for (int k = 0; k < BK; ++k) {
            float a[TM], b[TN];
#pragma unroll
            for (int i = 0; i < TM; ++i) a[i] = As[k][tr * TM + i];
#pragma unroll
            for (int j = 0; j < TN; ++j) b[j] = Bs[k][tc * TN + j];
#pragma unroll
            for (int i = 0; i < TM; ++i)
#pragma unroll
                for (int j = 0; j < TN; ++j)
                    acc[i][j] = fmaf(a[i], b[j], acc[i][j]);
        }
        __syncthreads();
    }
#pragma unroll
    for (int i = 0; i < TM; ++i) {
        int r = row0 + tr * TM + i;
#pragma unroll
        for (int j = 0; j < TN; ++j) {
            int c = col0 + tc * TN + j;
            float v = acc[i][j];
            if (b1) v += b1[c];
            if (b2) v += b2[c];
            if (ACT == 1) v = tanh_fast(v);
            out[(size_t)r * ldo + c] = v;
        }
    }
}

// ---------- small elementwise helpers ----------
__global__ void finalize_enc(const float* __restrict__ hx_sum,
                             const float* __restrict__ hy_sum,
                             float* __restrict__ hx_mean,
                             float* __restrict__ hcat) {
    int i = blockIdx.x * 256 + threadIdx.x;  // over 1024*512
    if (i >= BSZ * NH) return;
    int b = i >> 9, c = i & 511;
    float vx = hx_sum[i] * (1.0f / 64.0f);
    float vy = hy_sum[i] * (1.0f / 100.0f);
    hx_mean[i] = vx;
    hcat[b * 1024 + c] = vx;
    hcat[b * 1024 + 512 + c] = vy;
}

__global__ void build_dcin(const float* __restrict__ hx_mean,
                           const float* __restrict__ mu,
                           float* __restrict__ dcin) {
    int i = blockIdx.x * 256 + threadIdx.x;  // over 1024*640
    if (i >= BSZ * 640) return;
    int b = i / 640, c = i % 640;
    dcin[i] = (c < 512) ? hx_mean[b * 512 + c] : mu[b * NZ + (c - 512)];
}

// ---------- host ----------
extern "C" void kernel_launch(void* const* d_in, const int* in_sizes, int n_in,
                              void* d_out, int out_size, void* d_ws, size_t ws_size,
                              hipStream_t stream) {
    (void)in_sizes; (void)n_in; (void)out_size; (void)ws_size;
    auto F = [&](int i) { return (const float*)d_in[i]; };
    const float* x = F(0);
    const float* y = F(1);
    float* out = (float*)d_out;
    float* ws = (float*)d_ws;

    // workspace layout (floats)
    const size_t HX_SUM = 0;
    const size_t HY_SUM = HX_SUM + (size_t)BSZ * 512;
    const size_t HST = HY_SUM + (size_t)BSZ * 512;          // 4*2*1024*256
    const size_t CST = HST + (size_t)4 * 2 * BSZ * HB;      // 4*1024*256
    const size_t DEC_H = CST + (size_t)4 * BSZ * HB;        // 2*1024*512
    const size_t DEC_C = DEC_H + (size_t)2 * BSZ * NH;      // 1024*512
    const size_t ZEND = DEC_C + (size_t)BSZ * NH;
    const size_t HX_MEAN = ZEND;
    const size_t HCAT = HX_MEAN + (size_t)BSZ * 512;
    const size_t H1 = HCAT + (size_t)BSZ * 1024;  // reused by decoder mlp1
    const size_t H2 = H1 + (size_t)BSZ * 1024;    // reused by decoder mlp2
    const size_t DCIN = H2 + (size_t)BSZ * 512;
    const size_t CG = DCIN + (size_t)BSZ * 640;   // + 1024*2048

    hipMemsetAsync(ws, 0, ZEND * sizeof(float), stream);

    EncParams ep;
    const int wi[4] = {2, 6, 10, 14};
    for (int s = 0; s < 4; ++s) {
        ep.xin[s] = (s < 2) ? x : y;
        ep.wih[s] = F(wi[s]);
        ep.whh[s] = F(wi[s] + 1);
        ep.bih[s] = F(wi[s] + 2);
        ep.bhh[s] = F(wi[s] + 3);
        ep.Hst[s] = ws + HST + (size_t)s * 2 * BSZ * HB;
        ep.Cst[s] = ws + CST + (size_t)s * BSZ * HB;
    }
    ep.hsum[0] = ws + HX_SUM;
    ep.hsum[1] = ws + HX_SUM + 256;
    ep.hsum[2] = ws + HY_SUM;
    ep.hsum[3] = ws + HY_SUM + 256;

    for (int t = 0; t < TY; ++t) {
        int nb = (t < TX) ? 256 : 128;
        hipLaunchKernelGGL(enc_step, dim3(nb), dim3(256), 0, stream, ep, t);
    }

    finalize_enc<<<(BSZ * NH + 255) / 256, 256, 0, stream>>>(
        ws + HX_SUM, ws + HY_SUM, ws + HX_MEAN, ws + HCAT);

    // e_mlp: h1 = tanh(hcat @ w1^T + b1); h2 = tanh(h1 @ w2^T + b2)
    gemm_ba<64, 64, 1><<<dim3(16, 16), 256, 0, stream>>>(
        ws + HCAT, 1024, F(18), 1024, F(19), nullptr, ws + H1, 1024, 1024);
    gemm_ba<64, 64, 1><<<dim3(8, 16), 256, 0, stream>>>(
        ws + H1, 1024, F(20), 1024, F(21), nullptr, ws + H2, 512, 1024);

    float* mu = out + (size_t)HOR * BSZ * NY;
    float* lv = mu + (size_t)BSZ * NZ;
    gemm_ba<64, 64, 0><<<dim3(2, 16), 256, 0, stream>>>(
        ws + H2, 512, F(22), 512, F(23), nullptr, mu, NZ, 512);
    gemm_ba<64, 64, 0><<<dim3(2, 16), 256, 0, stream>>>(
        ws + H2, 512, F(24), 512, F(25), nullptr, lv, NZ, 512);

    build_dcin<<<(BSZ * 640 + 255) / 256, 256, 0, stream>>>(ws + HX_MEAN, mu, ws + DCIN);

    // const gates = dcin @ dr_wih[:, :640]^T + bih + bhh
    gemm_ba<64, 64, 0><<<dim3(32, 16), 256, 0, stream>>>(
        ws + DCIN, 640, F(26), 704, F(28), F(29), ws + CG, 2048, 640);

    for (int t = 0; t < HOR; ++t) {
        const float* yp = (t == 0) ? (x + (size_t)(TX - 1) * BSZ * NX)
                                   : (out + (size_t)(t - 1) * BSZ * NY);
        const float* Hc = ws + DEC_H + (size_t)(t & 1) * BSZ * NH;
        float* Hn = ws + DEC_H + (size_t)((t + 1) & 1) * BSZ * NH;
        dec_step<<<128, 256, 0, stream>>>(yp, F(26), F(27), ws + CG, Hc, Hn, ws + DEC_C);
        gemm_ba<64, 64, 1><<<dim3(16, 16), 256, 0, stream>>>(
            Hn, 512, F(30), 512, F(31), nullptr, ws + H1, 1024, 512);
        gemm_ba<64, 64, 1><<<dim3(8, 16), 256, 0, stream>>>(
            ws + H1, 1024, F(32), 1024, F(33), nullptr, ws + H2, 512, 1024);
        gemm_ba<16, 64, 0><<<dim3(1, 64), 256, 0, stream>>>(
            ws + H2, 512, F(34), 512, F(35), nullptr, out + (size_t)t * BSZ * NY, 64, 512);
    }
}

// Round 2
// 14962.379 us; speedup vs baseline: 3.5055x; 3.5055x over previous
//
#include <hip/hip_runtime.h>

// ---------------- constants ----------------
#define NXc 64
#define NYc 64
#define NZc 128
#define NHc 512
#define HBc 256
#define TXc 64
#define TYc 100
#define Bc 1024
#define HORc 100

typedef __attribute__((ext_vector_type(8))) short s16x8;
typedef __attribute__((ext_vector_type(4))) float f32x4;

#define MFMA_BF16 __builtin_amdgcn_mfma_f32_16x16x32_bf16

__device__ __forceinline__ float sigf(float x) { return 1.0f / (1.0f + __expf(-x)); }
__device__ __forceinline__ float tanh_fast(float x) {
    float e = __expf(2.0f * x);
    return 1.0f - 2.0f / (e + 1.0f);
}
__device__ __forceinline__ unsigned short bf16_rn(float x) {
    unsigned int u = __float_as_uint(x);
    u += 0x7FFFu + ((u >> 16) & 1u);
    return (unsigned short)(u >> 16);
}
// load 8 consecutive f32, split into hi/lo bf16 fragments
__device__ __forceinline__ void cvt_split8(const float* __restrict__ p, s16x8& hi, s16x8& lo) {
    float v[8];
    *(float4*)v = *(const float4*)p;
    *(float4*)(v + 4) = *(const float4*)(p + 4);
#pragma unroll
    for (int j = 0; j < 8; ++j) {
        unsigned short h = bf16_rn(v[j]);
        float hf = __uint_as_float(((unsigned int)h) << 16);
        unsigned short l = bf16_rn(v[j] - hf);
        hi[j] = (short)h;
        lo[j] = (short)l;
    }
}

// ---------------- weight prep: fragment-linear bf16 hi/lo ----------------
// W fused [N, K1+K2] from S1 [N,K1](ld1) and S2 [N,K2](ld2).
// out layout (ushort): [(s*NF + f)*64 + l]*16 + j  (j<8: hi, j>=8: lo)
__global__ __launch_bounds__(256) void prep_w(const float* __restrict__ S1, int ld1, int K1,
                                              const float* __restrict__ S2, int ld2,
                                              unsigned short* __restrict__ out, int NF) {
    int idx = blockIdx.x * 256 + threadIdx.x;  // (s*NF+f)*64 + l
    int l = idx & 63;
    int sf = idx >> 6;
    int f = sf % NF;
    int s = sf / NF;
    int n = f * 16 + (l & 15);
    int kb = s * 32 + ((l >> 4) << 3);
    unsigned short* o = out + (size_t)idx * 16;
#pragma unroll
    for (int j = 0; j < 8; ++j) {
        int k = kb + j;
        float v = (k < K1) ? S1[(size_t)n * ld1 + k] : S2[(size_t)n * ld2 + (k - K1)];
        unsigned short h = bf16_rn(v);
        float hf = __uint_as_float(((unsigned int)h) << 16);
        o[j] = h;
        o[8 + j] = bf16_rn(v - hf);
    }
}

// ---------------- encoder gates + cell (4 scans) ----------------
struct EncP {
    const unsigned short* Wp[4];
    const float* bih[4];
    const float* bhh[4];
    float* H[4];    // [2][B*HB] double buffer
    float* C[4];    // [B*HB]
    float* hsum[4]; // base + col offset, row stride 1024
    const float* x;
    const float* y;
};

__global__ __launch_bounds__(256) void enc_gates(EncP p, int t, int scanoff, int slshift) {
    int b = blockIdx.x;
    int rt = b >> slshift;
    int slice = b & ((1 << slshift) - 1);
    int scan = (slice >> 2) + scanoff;
    int ct = slice & 3;

    int T = (scan < 2) ? TXc : TYc;
    int tt = (scan & 1) ? (T - 1 - t) : t;
    const float* __restrict__ xt = ((scan < 2) ? p.x : p.y) + (size_t)tt * Bc * 64;
    const float* __restrict__ Hc = p.H[scan] + (size_t)(t & 1) * Bc * HBc;
    float* __restrict__ Hn = p.H[scan] + (size_t)((t + 1) & 1) * Bc * HBc;
    float* __restrict__ Cs = p.C[scan];
    const s16x8* __restrict__ wp = (const s16x8*)p.Wp[scan];
    const float* __restrict__ bih = p.bih[scan];
    const float* __restrict__ bhh = p.bhh[scan];
    float* __restrict__ hs = p.hsum[scan];

    int tid = threadIdx.x, l = tid & 63, wid = tid >> 6;
    int wr = wid & 1, wc = wid >> 1;
    int row0 = rt * 64 + wr * 32;
    int hc0 = ct * 64 + wc * 32;
    int lr = l & 15, lk8 = (l >> 4) * 8, l4 = (l >> 4) * 4;

    f32x4 acc[2][4][2];
#pragma unroll
    for (int q = 0; q < 4; ++q)
#pragma unroll
        for (int cf = 0; cf < 2; ++cf) {
            int col = q * 256 + hc0 + cf * 16 + lr;
            float bv = bih[col] + bhh[col];
            f32x4 iv = {bv, bv, bv, bv};
            acc[0][q][cf] = iv;
            acc[1][q][cf] = iv;
        }

    for (int s = 0; s < 10; ++s) {
        int kb = s * 32 + lk8;
        s16x8 ah[2], al[2];
#pragma unroll
        for (int rf = 0; rf < 2; ++rf) {
            int row = row0 + rf * 16 + lr;
            const float* ap = (kb < 64) ? (xt + (size_t)row * 64 + kb)
                                        : (Hc + (size_t)row * 256 + (kb - 64));
            cvt_split8(ap, ah[rf], al[rf]);
        }
#pragma unroll
        for (int q = 0; q < 4; ++q)
#pragma unroll
            for (int cf = 0; cf < 2; ++cf) {
                int f = (q * 256 + hc0 + cf * 16) >> 4;
                size_t wi = ((size_t)(s * 64 + f) * 64 + l) * 2;
                s16x8 wh = wp[wi], wl = wp[wi + 1];
#pragma unroll
                for (int rf = 0; rf < 2; ++rf) {
                    acc[rf][q][cf] = MFMA_BF16(ah[rf], wh, acc[rf][q][cf], 0, 0, 0);
                    acc[rf][q][cf] = MFMA_BF16(al[rf], wh, acc[rf][q][cf], 0, 0, 0);
                    acc[rf][q][cf] = MFMA_BF16(ah[rf], wl, acc[rf][q][cf], 0, 0, 0);
                }
            }
    }

#pragma unroll
    for (int rf = 0; rf < 2; ++rf)
#pragma unroll
        for (int cf = 0; cf < 2; ++cf) {
            int hc = hc0 + cf * 16 + lr;
#pragma unroll
            for (int r = 0; r < 4; ++r) {
                int row = row0 + rf * 16 + l4 + r;
                float gi = sigf(acc[rf][0][cf][r]);
                float gf = sigf(acc[rf][1][cf][r]);
                float gg = tanh_fast(acc[rf][2][cf][r]);
                float go = sigf(acc[rf][3][cf][r]);
                float cold = Cs[(size_t)row * 256 + hc];
                float cn = gf * cold + gi * gg;
                float hn = go * tanh_fast(cn);
                Cs[(size_t)row * 256 + hc] = cn;
                Hn[(size_t)row * 256 + hc] = hn;
                hs[(size_t)row * 1024 + hc] += hn;
            }
        }
}

// ---------------- decoder gates + cell ----------------
__global__ __launch_bounds__(256) void dec_gates(const float* __restrict__ yp,
                                                 const float* __restrict__ Hcur,
                                                 const unsigned short* __restrict__ Wpu,
                                                 const float* __restrict__ CG,
                                                 float* __restrict__ Hn,
                                                 float* __restrict__ Cs) {
    int b = blockIdx.x;
    int ct = b & 7, rt = b >> 3;
    const s16x8* __restrict__ wp = (const s16x8*)Wpu;

    int tid = threadIdx.x, l = tid & 63, wid = tid >> 6;
    int wr = wid & 1, wc = wid >> 1;
    int row0 = rt * 32 + wr * 16;
    int hc0 = ct * 64 + wc * 32;
    int lr = l & 15, lk8 = (l >> 4) * 8, l4 = (l >> 4) * 4;

    f32x4 acc[4][2];
#pragma unroll
    for (int q = 0; q < 4; ++q)
#pragma unroll
        for (int cf = 0; cf < 2; ++cf) {
            int col = q * 512 + hc0 + cf * 16 + lr;
#pragma unroll
            for (int r = 0; r < 4; ++r)
                acc[q][cf][r] = CG[(size_t)(row0 + l4 + r) * 2048 + col];
        }

    for (int s = 0; s < 18; ++s) {
        int kb = s * 32 + lk8;
        int row = row0 + lr;
        const float* ap = (kb < 64) ? (yp + (size_t)row * 64 + kb)
                                    : (Hcur + (size_t)row * 512 + (kb - 64));
        s16x8 ah, al;
        cvt_split8(ap, ah, al);
#pragma unroll
        for (int q = 0; q < 4; ++q)
#pragma unroll
            for (int cf = 0; cf < 2; ++cf) {
                int f = (q * 512 + hc0 + cf * 16) >> 4;
                size_t wi = ((size_t)(s * 128 + f) * 64 + l) * 2;
                s16x8 wh = wp[wi], wl = wp[wi + 1];
                acc[q][cf] = MFMA_BF16(ah, wh, acc[q][cf], 0, 0, 0);
                acc[q][cf] = MFMA_BF16(al, wh, acc[q][cf], 0, 0, 0);
                acc[q][cf] = MFMA_BF16(ah, wl, acc[q][cf], 0, 0, 0);
            }
    }

#pragma unroll
    for (int cf = 0; cf < 2; ++cf) {
        int hc = hc0 + cf * 16 + lr;
#pragma unroll
        for (int r = 0; r < 4; ++r) {
            int row = row0 + l4 + r;
            float gi = sigf(acc[0][cf][r]);
            float gf = sigf(acc[1][cf][r]);
            float gg = tanh_fast(acc[2][cf][r]);
            float go = sigf(acc[3][cf][r]);
            float cold = Cs[(size_t)row * 512 + hc];
            float cn = gf * cold + gi * gg;
            float hn = go * tanh_fast(cn);
            Cs[(size_t)row * 512 + hc] = cn;
            Hn[(size_t)row * 512 + hc] = hn;
        }
    }
}

// ---------------- generic out = act(A @ Wp^T + b1 + b2) ----------------
// A = [A1 | A2] (K1 cols from A1). Wp fragment-linear split-bf16, NF = N/16.
template <int BM, int BN, int ACT>
__global__ __launch_bounds__(256) void gemm_act(const float* __restrict__ A1, int ld1, int K1,
                                                const float* __restrict__ A2, int ld2,
                                                const unsigned short* __restrict__ Wpu, int KT, int NF,
                                                const float* __restrict__ b1,
                                                const float* __restrict__ b2,
                                                float* __restrict__ out, int ldo) {
    constexpr int RF = BM / 32;
    constexpr int CF = BN / 32;
    const s16x8* __restrict__ wp = (const s16x8*)Wpu;
    int tid = threadIdx.x, l = tid & 63, wid = tid >> 6;
    int wr = wid & 1, wc = wid >> 1;
    int row0 = blockIdx.y * BM + wr * (BM / 2);
    int col0 = blockIdx.x * BN + wc * (BN / 2);
    int lr = l & 15, lk8 = (l >> 4) * 8, l4 = (l >> 4) * 4;

    f32x4 acc[RF][CF];
#pragma unroll
    for (int rf = 0; rf < RF; ++rf)
#pragma unroll
        for (int cf = 0; cf < CF; ++cf) acc[rf][cf] = (f32x4){0.f, 0.f, 0.f, 0.f};

    int NS = KT / 32;
    for (int s = 0; s < NS; ++s) {
        int kb = s * 32 + lk8;
        s16x8 ah[RF], al[RF];
#pragma unroll
        for (int rf = 0; rf < RF; ++rf) {
            int row = row0 + rf * 16 + lr;
            const float* ap = (kb < K1) ? (A1 + (size_t)row * ld1 + kb)
                                        : (A2 + (size_t)row * ld2 + (kb - K1));
            cvt_split8(ap, ah[rf], al[rf]);
        }
#pragma unroll
        for (int cf = 0; cf < CF; ++cf) {
            int f = (col0 + cf * 16) >> 4;
            size_t wi = ((size_t)(s * NF + f) * 64 + l) * 2;
            s16x8 wh = wp[wi], wl = wp[wi + 1];
#pragma unroll
            for (int rf = 0; rf < RF; ++rf) {
                acc[rf][cf] = MFMA_BF16(ah[rf], wh, acc[rf][cf], 0, 0, 0);
                acc[rf][cf] = MFMA_BF16(al[rf], wh, acc[rf][cf], 0, 0, 0);
                acc[rf][cf] = MFMA_BF16(ah[rf], wl, acc[rf][cf], 0, 0, 0);
            }
        }
    }

#pragma unroll
    for (int rf = 0; rf < RF; ++rf)
#pragma unroll
        for (int cf = 0; cf < CF; ++cf) {
            int col = col0 + cf * 16 + lr;
            float bv = 0.f;
            if (b1) bv += b1[col];
            if (b2) bv += b2[col];
#pragma unroll
            for (int r = 0; r < 4; ++r) {
                float v = acc[rf][cf][r] + bv;
                if (ACT == 1) v = tanh_fast(v);
                int row = row0 + rf * 16 + l4 + r;
                out[(size_t)row * ldo + col] = v;
            }
        }
}

// ---------------- finalize: means -> HXY [1024][1024] ----------------
__global__ __launch_bounds__(256) void finalize_enc(const float* __restrict__ hs,
                                                    float* __restrict__ HXY) {
    int i = blockIdx.x * 256 + threadIdx.x;  // 1024*1024
    int col = i & 1023;
    HXY[i] = hs[i] * ((col < 512) ? (1.0f / 64.0f) : (1.0f / 100.0f));
}

// ---------------- host ----------------
extern "C" void kernel_launch(void* const* d_in, const int* in_sizes, int n_in,
                              void* d_out, int out_size, void* d_ws, size_t ws_size,
                              hipStream_t stream) {
    (void)in_sizes; (void)n_in; (void)out_size; (void)ws_size;
    auto F = [&](int i) { return (const float*)d_in[i]; };
    const float* x = F(0);
    const float* y = F(1);
    float* out = (float*)d_out;
    float* ws = (float*)d_ws;

    // ---- workspace layout (floats) ----
    const size_t HST = 0;                       // 4*2*1024*256 = 2,097,152  (-> CG later)
    const size_t CST = 2097152;                 // 4*1024*256  = 1,048,576  (-> H2 later)
    const size_t DECH = CST + 1048576;          // 2*1024*512  = 1,048,576
    const size_t DECC = DECH + 1048576;         // 1024*512    =   524,288
    const size_t HSUM = DECC + 524288;          // 1024*1024   = 1,048,576  (-> H1 later)
    const size_t HXY = HSUM + 1048576;          // 1024*1024
    const size_t WP0 = HXY + 1048576;

    float* CGp = ws + HST;
    float* H2p = ws + CST;
    float* H1p = ws + HSUM;
    float* HXYp = ws + HXY;

    // WP region offsets (floats; one float per hi/lo bf16 pair element)
    size_t off = WP0;
    auto alloc = [&](size_t nk) { size_t o = off; off += nk; return o; };
    const size_t WPX0 = alloc(1024 * 320);
    const size_t WPX1 = alloc(1024 * 320);
    const size_t WPE0 = alloc(1024 * 320);
    const size_t WPE1b = alloc(1024 * 320);
    const size_t WPM1 = alloc((size_t)1024 * 1024);
    const size_t WPM2 = alloc((size_t)512 * 1024);
    const size_t WPMU = alloc((size_t)128 * 512);
    const size_t WPLV = alloc((size_t)128 * 512);
    const size_t WPCG = alloc((size_t)2048 * 640);
    const size_t WPDG = alloc((size_t)2048 * 576);
    const size_t WPD1 = alloc((size_t)1024 * 512);
    const size_t WPD2 = alloc((size_t)512 * 1024);
    const size_t WPDO = alloc((size_t)64 * 512);

    auto U = [&](size_t o) { return (unsigned short*)(ws + o); };

    // ---- weight prep ----
    auto prep = [&](const float* s1, int ld1, int k1, const float* s2, int ld2,
                    size_t o, int N, int KT) {
        int threads = N * KT / 8;
        prep_w<<<threads / 256, 256, 0, stream>>>(s1, ld1, k1, s2 ? s2 : s1, ld2, U(o), N / 16);
    };
    prep(F(2), 64, 64, F(3), 256, WPX0, 1024, 320);
    prep(F(6), 64, 64, F(7), 256, WPX1, 1024, 320);
    prep(F(10), 64, 64, F(11), 256, WPE0, 1024, 320);
    prep(F(14), 64, 64, F(15), 256, WPE1b, 1024, 320);
    prep(F(18), 1024, 1024, nullptr, 0, WPM1, 1024, 1024);
    prep(F(20), 1024, 1024, nullptr, 0, WPM2, 512, 1024);
    prep(F(22), 512, 512, nullptr, 0, WPMU, 128, 512);
    prep(F(24), 512, 512, nullptr, 0, WPLV, 128, 512);
    prep(F(26), 704, 640, nullptr, 0, WPCG, 2048, 640);
    prep(F(26) + 640, 704, 64, F(27), 512, WPDG, 2048, 576);
    prep(F(30), 512, 512, nullptr, 0, WPD1, 1024, 512);
    prep(F(32), 1024, 1024, nullptr, 0, WPD2, 512, 1024);
    prep(F(34), 512, 512, nullptr, 0, WPDO, 64, 512);

    // zero states (HST, CST, DECH, DECC, HSUM)
    hipMemsetAsync(ws, 0, (size_t)5767168 * sizeof(float), stream);

    // ---- encoder ----
    EncP ep;
    const int wi[4] = {2, 6, 10, 14};
    const size_t wpo[4] = {WPX0, WPX1, WPE0, WPE1b};
    for (int s = 0; s < 4; ++s) {
        ep.Wp[s] = U(wpo[s]);
        ep.bih[s] = F(wi[s] + 2);
        ep.bhh[s] = F(wi[s] + 3);
        ep.H[s] = ws + HST + (size_t)s * 2 * Bc * HBc;
        ep.C[s] = ws + CST + (size_t)s * Bc * HBc;
        ep.hsum[s] = ws + HSUM + (size_t)s * 256;
    }
    ep.x = x;
    ep.y = y;

    for (int t = 0; t < TYc; ++t) {
        if (t < TXc)
            enc_gates<<<256, 256, 0, stream>>>(ep, t, 0, 4);
        else
            enc_gates<<<128, 256, 0, stream>>>(ep, t, 2, 3);
    }

    finalize_enc<<<4096, 256, 0, stream>>>(ws + HSUM, HXYp);

    float* mu = out + (size_t)HORc * Bc * NYc;
    float* lv = mu + (size_t)Bc * NZc;

    // e_mlp + heads
    gemm_act<64, 64, 1><<<dim3(16, 16), 256, 0, stream>>>(
        HXYp, 1024, 1024, HXYp, 0, U(WPM1), 1024, 64, F(19), nullptr, H1p, 1024);
    gemm_act<32, 64, 1><<<dim3(8, 32), 256, 0, stream>>>(
        H1p, 1024, 1024, H1p, 0, U(WPM2), 1024, 32, F(21), nullptr, H2p, 512);
    gemm_act<32, 64, 0><<<dim3(2, 32), 256, 0, stream>>>(
        H2p, 512, 512, H2p, 0, U(WPMU), 512, 8, F(23), nullptr, mu, 128);
    gemm_act<32, 64, 0><<<dim3(2, 32), 256, 0, stream>>>(
        H2p, 512, 512, H2p, 0, U(WPLV), 512, 8, F(25), nullptr, lv, 128);

    // const gates: [h_x | z] @ Wih[:, :640]^T + bih + bhh
    gemm_act<64, 64, 0><<<dim3(32, 16), 256, 0, stream>>>(
        HXYp, 1024, 512, mu, 128, U(WPCG), 640, 128, F(28), F(29), CGp, 2048);

    // ---- decoder ----
    for (int t = 0; t < HORc; ++t) {
        const float* yp = (t == 0) ? (x + (size_t)(TXc - 1) * Bc * NXc)
                                   : (out + (size_t)(t - 1) * Bc * NYc);
        const float* Hc = ws + DECH + (size_t)(t & 1) * Bc * NHc;
        float* Hn = ws + DECH + (size_t)((t + 1) & 1) * Bc * NHc;
        dec_gates<<<256, 256, 0, stream>>>(yp, Hc, U(WPDG), CGp, Hn, ws + DECC);
        gemm_act<64, 64, 1><<<dim3(16, 16), 256, 0, stream>>>(
            Hn, 512, 512, Hn, 0, U(WPD1), 512, 64, F(31), nullptr, H1p, 1024);
        gemm_act<32, 64, 1><<<dim3(8, 32), 256, 0, stream>>>(
            H1p, 1024, 1024, H1p, 0, U(WPD2), 1024, 32, F(33), nullptr, H2p, 512);
        gemm_act<32, 64, 0><<<dim3(1, 32), 256, 0, stream>>>(
            H2p, 512, 512, H2p, 0, U(WPDO), 512, 4, F(35), nullptr,
            out + (size_t)t * Bc * NYc, 64);
    }
}

// Round 3
// 13144.598 us; speedup vs baseline: 3.9903x; 1.1383x over previous
//
#include <hip/hip_runtime.h>

typedef unsigned short u16;
typedef __attribute__((ext_vector_type(8))) short s16x8;
typedef __attribute__((ext_vector_type(4))) float f32x4;

#define MFMA_BF16 __builtin_amdgcn_mfma_f32_16x16x32_bf16

__device__ __forceinline__ float sigf(float x) { return 1.0f / (1.0f + __expf(-x)); }
__device__ __forceinline__ float tanh_fast(float x) {
    float e = __expf(2.0f * x);
    return 1.0f - 2.0f / (e + 1.0f);
}
__device__ __forceinline__ u16 bf16_rn(float x) {
    unsigned int u = __float_as_uint(x);
    u += 0x7FFFu + ((u >> 16) & 1u);
    return (u16)(u >> 16);
}
__device__ __forceinline__ void split_store(float v, u16* __restrict__ ph,
                                            u16* __restrict__ pl, size_t off) {
    u16 h = bf16_rn(v);
    float hf = __uint_as_float(((unsigned int)h) << 16);
    ph[off] = h;
    pl[off] = bf16_rn(v - hf);
}

// ---------------- weight prep: fragment-linear bf16 hi/lo ----------------
// out (ushort): [(s*NF + f)*64 + l]*16 + j  (j<8: hi, j>=8: lo)
__global__ __launch_bounds__(256) void prep_w(const float* __restrict__ S1, int ld1, int K1,
                                              const float* __restrict__ S2, int ld2,
                                              u16* __restrict__ out, int NF) {
    int idx = blockIdx.x * 256 + threadIdx.x;
    int l = idx & 63;
    int sf = idx >> 6;
    int f = sf % NF;
    int s = sf / NF;
    int n = f * 16 + (l & 15);
    int kb = s * 32 + ((l >> 4) << 3);
    u16* o = out + (size_t)idx * 16;
#pragma unroll
    for (int j = 0; j < 8; ++j) {
        int k = kb + j;
        float v = (k < K1) ? S1[(size_t)n * ld1 + k] : S2[(size_t)n * ld2 + (k - K1)];
        u16 h = bf16_rn(v);
        float hf = __uint_as_float(((unsigned int)h) << 16);
        o[j] = h;
        o[8 + j] = bf16_rn(v - hf);
    }
}

// ---------------- activation prep: f32 -> hi/lo planes ----------------
__global__ __launch_bounds__(256) void prep_act(const float* __restrict__ in,
                                                u16* __restrict__ hi, u16* __restrict__ lo,
                                                int n4) {
    int i = blockIdx.x * 256 + threadIdx.x;
    if (i >= n4) return;
    float4 v = ((const float4*)in)[i];
    float vv[4] = {v.x, v.y, v.z, v.w};
    u16 h[4], l[4];
#pragma unroll
    for (int j = 0; j < 4; ++j) {
        h[j] = bf16_rn(vv[j]);
        float hf = __uint_as_float(((unsigned int)h[j]) << 16);
        l[j] = bf16_rn(vv[j] - hf);
    }
    ((ushort4*)hi)[i] = make_ushort4(h[0], h[1], h[2], h[3]);
    ((ushort4*)lo)[i] = make_ushort4(l[0], l[1], l[2], l[3]);
}

// ---------------- encoder gates + cell ----------------
struct EncP {
    const u16* Wp[4];
    const float* bih[4];
    const float* bhh[4];
    u16* Hh[4];
    u16* Hl[4];
    float* C[4];
    float* hsum[4];
    const u16* xh; const u16* xl;
    const u16* yh; const u16* yl;
};

__global__ __launch_bounds__(256) void enc_gates(EncP p, int t, int scanoff, int slshift) {
    int b = blockIdx.x;
    int rt = b >> slshift;
    int slice = b & ((1 << slshift) - 1);
    int scan = (slice >> 2) + scanoff;
    int ct = slice & 3;

    int T = (scan < 2) ? 64 : 100;
    int tt = (scan & 1) ? (T - 1 - t) : t;
    const u16* __restrict__ Xh = ((scan < 2) ? p.xh : p.yh) + (size_t)tt * 1024 * 64;
    const u16* __restrict__ Xl = ((scan < 2) ? p.xl : p.yl) + (size_t)tt * 1024 * 64;
    const u16* __restrict__ Hch = p.Hh[scan] + (size_t)(t & 1) * 1024 * 256;
    const u16* __restrict__ Hcl = p.Hl[scan] + (size_t)(t & 1) * 1024 * 256;
    u16* __restrict__ Hnh = p.Hh[scan] + (size_t)((t + 1) & 1) * 1024 * 256;
    u16* __restrict__ Hnl = p.Hl[scan] + (size_t)((t + 1) & 1) * 1024 * 256;
    float* __restrict__ Cs = p.C[scan];
    const s16x8* __restrict__ wp = (const s16x8*)p.Wp[scan];
    const float* __restrict__ bih = p.bih[scan];
    const float* __restrict__ bhh = p.bhh[scan];
    float* __restrict__ hs = p.hsum[scan];

    int tid = threadIdx.x, l = tid & 63, wid = tid >> 6;
    int wr = wid & 1, wc = wid >> 1;
    int row0 = rt * 64 + wr * 32;
    int hc0 = ct * 64 + wc * 32;
    int lr = l & 15, lk8 = (l >> 4) * 8, l4 = (l >> 4) * 4;

    f32x4 acc[2][4][2];
#pragma unroll
    for (int q = 0; q < 4; ++q)
#pragma unroll
        for (int cf = 0; cf < 2; ++cf) {
            int col = q * 256 + hc0 + cf * 16 + lr;
            float bv = bih[col] + bhh[col];
            f32x4 iv = {bv, bv, bv, bv};
            acc[0][q][cf] = iv;
            acc[1][q][cf] = iv;
        }

    for (int s = 0; s < 10; ++s) {
        int kb = s * 32 + lk8;
        s16x8 ah[2], al[2];
#pragma unroll
        for (int rf = 0; rf < 2; ++rf) {
            int row = row0 + rf * 16 + lr;
            size_t off = (kb < 64) ? ((size_t)row * 64 + kb)
                                   : ((size_t)row * 256 + (kb - 64));
            const u16* ph = (kb < 64) ? Xh : Hch;
            const u16* pl2 = (kb < 64) ? Xl : Hcl;
            ah[rf] = *(const s16x8*)(ph + off);
            al[rf] = *(const s16x8*)(pl2 + off);
        }
#pragma unroll
        for (int q = 0; q < 4; ++q)
#pragma unroll
            for (int cf = 0; cf < 2; ++cf) {
                int f = (q * 256 + hc0 + cf * 16) >> 4;
                size_t wi = ((size_t)(s * 64 + f) * 64 + l) * 2;
                s16x8 wh = wp[wi], wl = wp[wi + 1];
#pragma unroll
                for (int rf = 0; rf < 2; ++rf) {
                    acc[rf][q][cf] = MFMA_BF16(ah[rf], wh, acc[rf][q][cf], 0, 0, 0);
                    acc[rf][q][cf] = MFMA_BF16(al[rf], wh, acc[rf][q][cf], 0, 0, 0);
                    acc[rf][q][cf] = MFMA_BF16(ah[rf], wl, acc[rf][q][cf], 0, 0, 0);
                }
            }
    }

#pragma unroll
    for (int rf = 0; rf < 2; ++rf)
#pragma unroll
        for (int cf = 0; cf < 2; ++cf) {
            int hc = hc0 + cf * 16 + lr;
#pragma unroll
            for (int r = 0; r < 4; ++r) {
                int row = row0 + rf * 16 + l4 + r;
                float gi = sigf(acc[rf][0][cf][r]);
                float gf = sigf(acc[rf][1][cf][r]);
                float gg = tanh_fast(acc[rf][2][cf][r]);
                float go = sigf(acc[rf][3][cf][r]);
                size_t co = (size_t)row * 256 + hc;
                float cn = gf * Cs[co] + gi * gg;
                float hn = go * tanh_fast(cn);
                Cs[co] = cn;
                split_store(hn, Hnh, Hnl, co);
                hs[(size_t)row * 1024 + hc] += hn;
            }
        }
}

// ---------------- decoder gates + cell (64-row tiles) ----------------
__global__ __launch_bounds__(256) void dec_gates(const u16* __restrict__ yph,
                                                 const u16* __restrict__ ypl,
                                                 const u16* __restrict__ Hch,
                                                 const u16* __restrict__ Hcl,
                                                 const u16* __restrict__ Wpu,
                                                 const float* __restrict__ CG,
                                                 u16* __restrict__ Hnh,
                                                 u16* __restrict__ Hnl,
                                                 float* __restrict__ Cs) {
    int b = blockIdx.x;
    int ct = b & 7, rt = b >> 3;  // ct in low bits -> slice-per-XCD
    const s16x8* __restrict__ wp = (const s16x8*)Wpu;

    int tid = threadIdx.x, l = tid & 63, wid = tid >> 6;
    int wr = wid & 1, wc = wid >> 1;
    int row0 = rt * 64 + wr * 32;
    int hc0 = ct * 64 + wc * 32;
    int lr = l & 15, lk8 = (l >> 4) * 8, l4 = (l >> 4) * 4;

    f32x4 acc[2][4][2];
#pragma unroll
    for (int rf = 0; rf < 2; ++rf)
#pragma unroll
        for (int q = 0; q < 4; ++q)
#pragma unroll
            for (int cf = 0; cf < 2; ++cf) {
                int col = q * 512 + hc0 + cf * 16 + lr;
#pragma unroll
                for (int r = 0; r < 4; ++r)
                    acc[rf][q][cf][r] = CG[(size_t)(row0 + rf * 16 + l4 + r) * 2048 + col];
            }

    for (int s = 0; s < 18; ++s) {
        int kb = s * 32 + lk8;
        s16x8 ah[2], al[2];
#pragma unroll
        for (int rf = 0; rf < 2; ++rf) {
            int row = row0 + rf * 16 + lr;
            size_t off = (kb < 64) ? ((size_t)row * 64 + kb)
                                   : ((size_t)row * 512 + (kb - 64));
            const u16* ph = (kb < 64) ? yph : Hch;
            const u16* pl2 = (kb < 64) ? ypl : Hcl;
            ah[rf] = *(const s16x8*)(ph + off);
            al[rf] = *(const s16x8*)(pl2 + off);
        }
#pragma unroll
        for (int q = 0; q < 4; ++q)
#pragma unroll
            for (int cf = 0; cf < 2; ++cf) {
                int f = (q * 512 + hc0 + cf * 16) >> 4;
                size_t wi = ((size_t)(s * 128 + f) * 64 + l) * 2;
                s16x8 wh = wp[wi], wl = wp[wi + 1];
#pragma unroll
                for (int rf = 0; rf < 2; ++rf) {
                    acc[rf][q][cf] = MFMA_BF16(ah[rf], wh, acc[rf][q][cf], 0, 0, 0);
                    acc[rf][q][cf] = MFMA_BF16(al[rf], wh, acc[rf][q][cf], 0, 0, 0);
                    acc[rf][q][cf] = MFMA_BF16(ah[rf], wl, acc[rf][q][cf], 0, 0, 0);
                }
            }
    }

#pragma unroll
    for (int rf = 0; rf < 2; ++rf)
#pragma unroll
        for (int cf = 0; cf < 2; ++cf) {
            int hc = hc0 + cf * 16 + lr;
#pragma unroll
            for (int r = 0; r < 4; ++r) {
                int row = row0 + rf * 16 + l4 + r;
                float gi = sigf(acc[rf][0][cf][r]);
                float gf = sigf(acc[rf][1][cf][r]);
                float gg = tanh_fast(acc[rf][2][cf][r]);
                float go = sigf(acc[rf][3][cf][r]);
                size_t co = (size_t)row * 512 + hc;
                float cn = gf * Cs[co] + gi * gg;
                float hn = go * tanh_fast(cn);
                Cs[co] = cn;
                split_store(hn, Hnh, Hnl, co);
            }
        }
}

// ---------------- generic: out = act(A @ Wp^T + b1 + b2) ----------------
// A given as hi/lo planes, optionally stitched [A1 | A2] at K1.
template <int BM, int BN, int ACT, int WF32, int WPL>
__global__ __launch_bounds__(256) void gemm_pl(
    const u16* __restrict__ A1h, const u16* __restrict__ A1l, int ld1, int K1,
    const u16* __restrict__ A2h, const u16* __restrict__ A2l, int ld2,
    const u16* __restrict__ Wpu, int NF,
    const float* __restrict__ b1, const float* __restrict__ b2,
    float* __restrict__ outF, int ldo,
    u16* __restrict__ Oh, u16* __restrict__ Ol, int ldop, int KT) {
    constexpr int RF = BM / 32;
    constexpr int CF = BN / 32;
    const s16x8* __restrict__ wp = (const s16x8*)Wpu;
    int tid = threadIdx.x, l = tid & 63, wid = tid >> 6;
    int wr = wid & 1, wc = wid >> 1;
    int row0 = blockIdx.y * BM + wr * (BM / 2);
    int col0 = blockIdx.x * BN + wc * (BN / 2);
    int lr = l & 15, lk8 = (l >> 4) * 8, l4 = (l >> 4) * 4;

    f32x4 acc[RF][CF];
#pragma unroll
    for (int rf = 0; rf < RF; ++rf)
#pragma unroll
        for (int cf = 0; cf < CF; ++cf) acc[rf][cf] = (f32x4){0.f, 0.f, 0.f, 0.f};

    int NS = KT / 32;
    for (int s = 0; s < NS; ++s) {
        int kb = s * 32 + lk8;
        s16x8 ah[RF], al[RF];
#pragma unroll
        for (int rf = 0; rf < RF; ++rf) {
            int row = row0 + rf * 16 + lr;
            size_t off = (kb < K1) ? ((size_t)row * ld1 + kb)
                                   : ((size_t)row * ld2 + (kb - K1));
            const u16* ph = (kb < K1) ? A1h : A2h;
            const u16* pl2 = (kb < K1) ? A1l : A2l;
            ah[rf] = *(const s16x8*)(ph + off);
            al[rf] = *(const s16x8*)(pl2 + off);
        }
#pragma unroll
        for (int cf = 0; cf < CF; ++cf) {
            int f = (col0 + cf * 16) >> 4;
            size_t wi = ((size_t)(s * NF + f) * 64 + l) * 2;
            s16x8 wh = wp[wi], wl = wp[wi + 1];
#pragma unroll
            for (int rf = 0; rf < RF; ++rf) {
                acc[rf][cf] = MFMA_BF16(ah[rf], wh, acc[rf][cf], 0, 0, 0);
                acc[rf][cf] = MFMA_BF16(al[rf], wh, acc[rf][cf], 0, 0, 0);
                acc[rf][cf] = MFMA_BF16(ah[rf], wl, acc[rf][cf], 0, 0, 0);
            }
        }
    }

#pragma unroll
    for (int rf = 0; rf < RF; ++rf)
#pragma unroll
        for (int cf = 0; cf < CF; ++cf) {
            int col = col0 + cf * 16 + lr;
            float bv = 0.f;
            if (b1) bv += b1[col];
            if (b2) bv += b2[col];
#pragma unroll
            for (int r = 0; r < 4; ++r) {
                float v = acc[rf][cf][r] + bv;
                if (ACT == 1) v = tanh_fast(v);
                int row = row0 + rf * 16 + l4 + r;
                if (WF32) outF[(size_t)row * ldo + col] = v;
                if (WPL) split_store(v, Oh, Ol, (size_t)row * ldop + col);
            }
        }
}

// ---------------- finalize: hsum -> HXY planes ----------------
__global__ __launch_bounds__(256) void finalize_enc(const float* __restrict__ hs,
                                                    u16* __restrict__ Hh,
                                                    u16* __restrict__ Hl) {
    int i = blockIdx.x * 256 + threadIdx.x;  // 1024*1024
    int col = i & 1023;
    float v = hs[i] * ((col < 512) ? (1.0f / 64.0f) : (1.0f / 100.0f));
    split_store(v, Hh, Hl, (size_t)i);
}

// ---------------- host ----------------
extern "C" void kernel_launch(void* const* d_in, const int* in_sizes, int n_in,
                              void* d_out, int out_size, void* d_ws, size_t ws_size,
                              hipStream_t stream) {
    (void)in_sizes; (void)n_in; (void)out_size; (void)ws_size;
    auto F = [&](int i) { return (const float*)d_in[i]; };
    const float* x = F(0);
    const float* y = F(1);
    float* out = (float*)d_out;
    char* base = (char*)d_ws;
    const size_t MB = 1ull << 20;

    // ---- region carve (phase-overlapped) ----
    float* CGf   = (float*)(base + 0);        // 8 MB, decoder phase
    float* hsumf = (float*)(base + 0);        // 4 MB, encoder phase (CG overwrites later)
    float* encC  = (float*)(base + 4 * MB);   // 4 MB, encoder phase
    float* decC  = (float*)(base + 8 * MB);   // 2 MB
    u16* encHh = (u16*)(base + 10 * MB);      // 4 MB  [4 scans][2 buf][1024*256]
    u16* encHl = (u16*)(base + 14 * MB);      // 4 MB
    u16* decHh = encHh;                       // 2 MB  [2 buf][1024*512] (after encoder)
    u16* decHl = encHl;
    u16* HXYh = (u16*)(base + 18 * MB);
    u16* HXYl = (u16*)(base + 20 * MB);
    u16* H1h = (u16*)(base + 22 * MB);
    u16* H1l = (u16*)(base + 24 * MB);
    u16* H2h = (u16*)(base + 26 * MB);
    u16* H2l = (u16*)(base + 27 * MB);
    u16* muh = (u16*)(base + 28 * MB);
    u16* mul_ = (u16*)(base + 28 * MB + 256 * 1024);
    u16* Ydh = (u16*)(base + 28 * MB + 512 * 1024);
    u16* Ydl = (u16*)(base + 28 * MB + 640 * 1024);
    u16* Xh = (u16*)(base + 29 * MB);   // 8 MB
    u16* Xl = (u16*)(base + 37 * MB);   // 8 MB
    u16* Yh = (u16*)(base + 45 * MB);   // 12.8 MB
    u16* Yl = (u16*)(base + 58 * MB);   // 12.8 MB
    u16* W0 = (u16*)(base + 71 * MB);   // weights ~26.3 MB

    size_t wo = 0;
    auto walloc = [&](size_t elems) { u16* p = W0 + wo; wo += elems * 2; return p; };
    u16* WPX0 = walloc((size_t)1024 * 320);
    u16* WPX1 = walloc((size_t)1024 * 320);
    u16* WPE0 = walloc((size_t)1024 * 320);
    u16* WPE1 = walloc((size_t)1024 * 320);
    u16* WPM1 = walloc((size_t)1024 * 1024);
    u16* WPM2 = walloc((size_t)512 * 1024);
    u16* WPMU = walloc((size_t)128 * 512);
    u16* WPLV = walloc((size_t)128 * 512);
    u16* WPCG = walloc((size_t)2048 * 640);
    u16* WPDG = walloc((size_t)2048 * 576);
    u16* WPD1 = walloc((size_t)1024 * 512);
    u16* WPD2 = walloc((size_t)512 * 1024);
    u16* WPDO = walloc((size_t)64 * 512);

    // ---- weight + activation prep ----
    auto prep = [&](const float* s1, int ld1, int k1, const float* s2, int ld2,
                    u16* o, int N, int KT) {
        prep_w<<<(N * KT / 8) / 256, 256, 0, stream>>>(s1, ld1, k1, s2, ld2, o, N / 16);
    };
    prep(F(2), 64, 64, F(3), 256, WPX0, 1024, 320);
    prep(F(6), 64, 64, F(7), 256, WPX1, 1024, 320);
    prep(F(10), 64, 64, F(11), 256, WPE0, 1024, 320);
    prep(F(14), 64, 64, F(15), 256, WPE1, 1024, 320);
    prep(F(18), 1024, 1024, F(18), 1024, WPM1, 1024, 1024);
    prep(F(20), 1024, 1024, F(20), 1024, WPM2, 512, 1024);
    prep(F(22), 512, 512, F(22), 512, WPMU, 128, 512);
    prep(F(24), 512, 512, F(24), 512, WPLV, 128, 512);
    prep(F(26), 704, 640, F(26), 704, WPCG, 2048, 640);
    prep(F(26) + 640, 704, 64, F(27), 512, WPDG, 2048, 576);
    prep(F(30), 512, 512, F(30), 512, WPD1, 1024, 512);
    prep(F(32), 1024, 1024, F(32), 1024, WPD2, 512, 1024);
    prep(F(34), 512, 512, F(34), 512, WPDO, 64, 512);

    prep_act<<<4096, 256, 0, stream>>>(x, Xh, Xl, 64 * 1024 * 64 / 4);
    prep_act<<<6400, 256, 0, stream>>>(y, Yh, Yl, 100 * 1024 * 64 / 4);

    // zero: hsum+encC (0..8MB), decC (8..10MB), encH planes (10..18MB)
    hipMemsetAsync(base, 0, 18 * MB, stream);

    // ---- encoder ----
    EncP ep;
    const int wi[4] = {2, 6, 10, 14};
    u16* wps[4] = {WPX0, WPX1, WPE0, WPE1};
    for (int s = 0; s < 4; ++s) {
        ep.Wp[s] = wps[s];
        ep.bih[s] = F(wi[s] + 2);
        ep.bhh[s] = F(wi[s] + 3);
        ep.Hh[s] = encHh + (size_t)s * 2 * 1024 * 256;
        ep.Hl[s] = encHl + (size_t)s * 2 * 1024 * 256;
        ep.C[s] = encC + (size_t)s * 1024 * 256;
        ep.hsum[s] = hsumf + (size_t)s * 256;
    }
    ep.xh = Xh; ep.xl = Xl; ep.yh = Yh; ep.yl = Yl;

    for (int t = 0; t < 100; ++t) {
        if (t < 64)
            enc_gates<<<256, 256, 0, stream>>>(ep, t, 0, 4);
        else
            enc_gates<<<128, 256, 0, stream>>>(ep, t, 2, 3);
    }

    finalize_enc<<<4096, 256, 0, stream>>>(hsumf, HXYh, HXYl);

    float* muF = out + (size_t)100 * 1024 * 64;
    float* lvF = muF + (size_t)1024 * 128;

    gemm_pl<64, 64, 1, 0, 1><<<dim3(16, 16), 256, 0, stream>>>(
        HXYh, HXYl, 1024, 1024, HXYh, HXYl, 1024, WPM1, 64, F(19), nullptr,
        nullptr, 0, H1h, H1l, 1024, 1024);
    gemm_pl<32, 64, 1, 0, 1><<<dim3(8, 32), 256, 0, stream>>>(
        H1h, H1l, 1024, 1024, H1h, H1l, 1024, WPM2, 32, F(21), nullptr,
        nullptr, 0, H2h, H2l, 512, 1024);
    gemm_pl<32, 64, 0, 1, 1><<<dim3(2, 32), 256, 0, stream>>>(
        H2h, H2l, 512, 512, H2h, H2l, 512, WPMU, 8, F(23), nullptr,
        muF, 128, muh, mul_, 128, 512);
    gemm_pl<32, 64, 0, 1, 0><<<dim3(2, 32), 256, 0, stream>>>(
        H2h, H2l, 512, 512, H2h, H2l, 512, WPLV, 8, F(25), nullptr,
        lvF, 128, nullptr, nullptr, 0, 512);
    // const gates: [h_x | z] @ Wih[:, :640]^T + bih + bhh  (overwrites hsum region)
    gemm_pl<64, 64, 0, 1, 0><<<dim3(32, 16), 256, 0, stream>>>(
        HXYh, HXYl, 1024, 512, muh, mul_, 128, WPCG, 128, F(28), F(29),
        CGf, 2048, nullptr, nullptr, 0, 640);

    // zero decoder H planes + C (encH region is dead now)
    hipMemsetAsync(decHh, 0, (size_t)2 * 1024 * 512 * 2, stream);
    hipMemsetAsync(decHl, 0, (size_t)2 * 1024 * 512 * 2, stream);
    hipMemsetAsync(decC, 0, (size_t)1024 * 512 * 4, stream);

    // ---- decoder ----
    for (int t = 0; t < 100; ++t) {
        const u16* yph = (t == 0) ? (Xh + (size_t)63 * 1024 * 64) : Ydh;
        const u16* ypl = (t == 0) ? (Xl + (size_t)63 * 1024 * 64) : Ydl;
        const u16* Hch = decHh + (size_t)(t & 1) * 1024 * 512;
        const u16* Hcl = decHl + (size_t)(t & 1) * 1024 * 512;
        u16* Hnh = decHh + (size_t)((t + 1) & 1) * 1024 * 512;
        u16* Hnl = decHl + (size_t)((t + 1) & 1) * 1024 * 512;
        dec_gates<<<128, 256, 0, stream>>>(yph, ypl, Hch, Hcl, WPDG, CGf, Hnh, Hnl, decC);
        gemm_pl<64, 64, 1, 0, 1><<<dim3(16, 16), 256, 0, stream>>>(
            Hnh, Hnl, 512, 512, Hnh, Hnl, 512, WPD1, 64, F(31), nullptr,
            nullptr, 0, H1h, H1l, 1024, 512);
        gemm_pl<32, 64, 1, 0, 1><<<dim3(8, 32), 256, 0, stream>>>(
            H1h, H1l, 1024, 1024, H1h, H1l, 1024, WPD2, 32, F(33), nullptr,
            nullptr, 0, H2h, H2l, 512, 1024);
        gemm_pl<32, 64, 0, 1, 1><<<dim3(1, 32), 256, 0, stream>>>(
            H2h, H2l, 512, 512, H2h, H2l, 512, WPDO, 4, F(35), nullptr,
            out + (size_t)t * 1024 * 64, 64, Ydh, Ydl, 64, 512);
    }
}